// Round 14
// baseline (805.073 us; speedup 1.0000x reference)
//
#include <hip/hip_runtime.h>
#include <math.h>

// Problem constants
#define NB   32
#define NP   128
#define NM   4096        // NB*NP matrices per type
#define NMAT3 12288      // 3*NM (Q,K,V)

typedef float v2f __attribute__((ext_vector_type(2)));

// ---- packed dual-FP32 via VOP3P inline asm (CDNA4 keeps v_pk_*_f32).
// R13 evidence: wall time tracks instruction count (issue-bound) and
// VALUBusy ~91% is real, implying hipcc SCALARIZES v2f math. Force pk.
// pk_fma is two IEEE fmas -> bitwise identical to the scalar version.
__device__ __forceinline__ v2f pk_fma(v2f a, v2f b, v2f c) {
    v2f d;
    asm("v_pk_fma_f32 %0, %1, %2, %3" : "=v"(d) : "v"(a), "v"(b), "v"(c));
    return d;
}
__device__ __forceinline__ v2f pk_mul(v2f a, v2f b) {
    v2f d;
    asm("v_pk_mul_f32 %0, %1, %2" : "=v"(d) : "v"(a), "v"(b));
    return d;
}
__device__ __forceinline__ v2f pk_add(v2f a, v2f b) {
    v2f d;
    asm("v_pk_add_f32 %0, %1, %2" : "=v"(d) : "v"(a), "v"(b));
    return d;
}

__device__ __forceinline__ v2f v2fma(v2f x, v2f y, v2f z) {
#if defined(__has_builtin)
#if __has_builtin(__builtin_elementwise_fma)
    return __builtin_elementwise_fma(x, y, z);
#else
    return (v2f){fmaf(x.x, y.x, z.x), fmaf(x.y, y.y, z.y)};
#endif
#else
    return (v2f){fmaf(x.x, y.x, z.x), fmaf(x.y, y.y, z.y)};
#endif
}

// ---------------------------------------------------------------------------
// K1: bimap — Q/K/V[b,p] = W * x[b,p] * W^T   (x: 64x64 SPD, W: 32x64)
// ---------------------------------------------------------------------------
__global__ __launch_bounds__(256) void bimap_kernel(
    const float* __restrict__ x, const float* __restrict__ Wq,
    const float* __restrict__ Wk, const float* __restrict__ Wv,
    float* __restrict__ qkv)
{
    __shared__ __align__(16) float S[64 * 64];
    __shared__ float Wl[32 * 65];
    __shared__ float T[32 * 65];
    const int tid = threadIdx.x;
    const int bp  = blockIdx.x;
    const float* xs = x + (size_t)bp * 4096;
#pragma unroll
    for (int k = 0; k < 4; ++k) {
        int idx = tid * 4 + k * 1024;
        *(float4*)&S[idx] = *(const float4*)&xs[idx];
    }
    const int o32 = tid & 31;
    const int grp = tid >> 5;
#pragma unroll 1
    for (int w = 0; w < 3; ++w) {
        const float* Wsrc = (w == 0) ? Wq : ((w == 1) ? Wk : Wv);
        __syncthreads();
#pragma unroll
        for (int k = 0; k < 8; ++k) {
            int f = tid + k * 256;
            Wl[(f >> 6) * 65 + (f & 63)] = Wsrc[f];
        }
        __syncthreads();
        {
            float acc[8];
#pragma unroll
            for (int jj = 0; jj < 8; ++jj) acc[jj] = 0.f;
            const int j0 = grp * 8;
#pragma unroll 4
            for (int i = 0; i < 64; ++i) {
                float wv = Wl[o32 * 65 + i];
                const float4 s0 = *(const float4*)&S[i * 64 + j0];
                const float4 s1 = *(const float4*)&S[i * 64 + j0 + 4];
                acc[0] = fmaf(wv, s0.x, acc[0]);
                acc[1] = fmaf(wv, s0.y, acc[1]);
                acc[2] = fmaf(wv, s0.z, acc[2]);
                acc[3] = fmaf(wv, s0.w, acc[3]);
                acc[4] = fmaf(wv, s1.x, acc[4]);
                acc[5] = fmaf(wv, s1.y, acc[5]);
                acc[6] = fmaf(wv, s1.z, acc[6]);
                acc[7] = fmaf(wv, s1.w, acc[7]);
            }
#pragma unroll
            for (int jj = 0; jj < 8; ++jj) T[o32 * 65 + j0 + jj] = acc[jj];
        }
        __syncthreads();
        {
            float oacc[4] = {0.f, 0.f, 0.f, 0.f};
            const int kcol = tid & 31;
            const int ob   = grp * 4;
#pragma unroll 4
            for (int j = 0; j < 64; ++j) {
                float wv = Wl[kcol * 65 + j];
#pragma unroll
                for (int cc = 0; cc < 4; ++cc)
                    oacc[cc] = fmaf(T[(ob + cc) * 65 + j], wv, oacc[cc]);
            }
            float* dst = qkv + ((size_t)w * NM + bp) * 1024;
#pragma unroll
            for (int cc = 0; cc < 4; ++cc)
                dst[(ob + cc) * 32 + kcol] = oacc[cc];
        }
    }
}

// ---------------------------------------------------------------------------
// K2: batched logm via one-sided Jacobi, lane-per-pair systolic, half-column
// per lane (R9 structure). Hot blocks (dot16, jupdate column update) in
// packed dual-fp32. Writes log M in place + ssq.
// ---------------------------------------------------------------------------
__device__ __forceinline__ float ror1(float x) {   // dest i <- src (i-1)&15
    return __int_as_float(__builtin_amdgcn_mov_dpp(
        __float_as_int(x), 0x121, 0xf, 0xf, true));
}
__device__ __forceinline__ float ror15(float x) {  // dest i <- src (i+1)&15
    return __int_as_float(__builtin_amdgcn_mov_dpp(
        __float_as_int(x), 0x12F, 0xf, 0xf, true));
}

__device__ __forceinline__ float dot16(const v2f (&x)[8], const v2f (&y)[8]) {
    v2f g0 = {0.f, 0.f}, g1 = {0.f, 0.f};
#pragma unroll
    for (int j = 0; j < 8; j += 2) {
        g0 = pk_fma(x[j], y[j], g0);
        g1 = pk_fma(x[j + 1], y[j + 1], g1);
    }
    v2f g = pk_add(g0, g1);
    return g.x + g.y;
}

__device__ __forceinline__ void jupdate(v2f (&a)[8], v2f (&b)[8],
                                        float& alA, float& alB,
                                        float gm, bool doRot) {
    const float zeta = (alB - alA) * __builtin_amdgcn_rcpf(2.0f * gm);
    float tt = copysignf(__builtin_amdgcn_rcpf(
        fabsf(zeta) + __builtin_amdgcn_sqrtf(fmaf(zeta, zeta, 1.0f))), zeta);
    float cc = __builtin_amdgcn_rsqf(fmaf(tt, tt, 1.0f));
    float sn = cc * tt;
    if (!doRot) { cc = 1.0f; sn = 0.0f; }   // NaN-safe when gm==0
    const v2f c2 = {cc, cc}, spv = {sn, sn}, smv = {-sn, -sn};
#pragma unroll
    for (int j = 0; j < 8; ++j) {
        const v2f ao = a[j], bo = b[j];
        const v2f ta = pk_mul(smv, bo);   // -s*b
        const v2f tb = pk_mul(spv, ao);   //  s*a
        a[j] = pk_fma(c2, ao, ta);
        b[j] = pk_fma(c2, bo, tb);
    }
    const float cq = cc * cc, sq = sn * sn, cs2 = 2.0f * cc * sn * gm;
    const float nA = fmaf(cq, alA, fmaf(sq, alB, -cs2));
    const float nB = fmaf(sq, alA, fmaf(cq, alB, cs2));
    alA = nA; alB = nB;
}

__global__ __launch_bounds__(256) void log_eig_kernel(
    const float* in, float* out, float* __restrict__ ssq)
{
    __shared__ __align__(16) float Uld[4][32 * 36];   // per-wave slice
    __shared__ __align__(16) float fld[4][32];
    const int tid  = threadIdx.x;
    const int wv   = tid >> 6;           // wave in block (0..3)
    const int lane = tid & 63;
    const int idx  = lane & 15;          // pair slot within row
    const int h    = (lane >> 4) & 1;    // row-half of the matrix
    const int mw   = lane >> 5;          // matrix within wave (0/1)
    const bool l14 = (idx == 14), l15 = (idx == 15);
    const int cA = idx * 2, cB = idx * 2 + 1;   // initial owned columns
    const int r0 = h * 16;               // first row this lane holds
    const size_t m0 = (size_t)blockIdx.x * 8 + wv * 2;

    const float* src = in + (m0 + mw) * 1024;
    v2f a[8], b[8];
#pragma unroll
    for (int j = 0; j < 8; ++j) {
        const int rA = r0 + 2 * j, rB = rA + 1;
        float2 lo = *(const float2*)&src[rA * 32 + cA];   // (A[rA][cA], A[rA][cB])
        float2 hi = *(const float2*)&src[rB * 32 + cA];
        a[j] = (v2f){lo.x, hi.x};
        b[j] = (v2f){lo.y, hi.y};
    }

    // ---- Jacobi sweeps: 31 systolic rounds/sweep (all per-wave) ----
    for (int sweep = 0; sweep < 10; ++sweep) {
        float alA = dot16(a, a); alA += __shfl_xor(alA, 16);
        float alB = dot16(b, b); alB += __shfl_xor(alB, 16);
        bool bigrot = false;
        for (int r = 0; r < 31; ++r) {
            float gm = dot16(a, b);
            gm += __shfl_xor(gm, 16);
            const float t  = alA * alB;
            const float g2 = gm * gm;
            const bool doRot = g2 > 1e-10f * t;
            bigrot |= (g2 > 1e-7f * t);
            if (__any((int)doRot))
                jupdate(a, b, alA, alB, gm, doRot);
            // ---- migrate (R5-verified circle schedule, per 16-lane row) ----
            {
                const float alAg = ror1(alA), alBg = ror15(alB), alAo = alA;
                alA = l15 ? alBg : alAg;
                alB = l15 ? alB : (l14 ? alAo : alBg);
            }
#pragma unroll
            for (int j = 0; j < 8; ++j) {
                const v2f ao = a[j], bo = b[j];
                v2f t2, an;
                t2.x = ror15(bo.x); t2.y = ror15(bo.y);
                an.x = ror1(ao.x);  an.y = ror1(ao.y);
                a[j] = l15 ? t2 : an;
                v2f bn = l14 ? ao : t2;
                b[j] = l15 ? bo : bn;
            }
        }
        if (!__any((int)bigrot)) break;   // sweep saw only sub-1e-7 angles
    }

    // ---- finals (each column's sigma; both halves identical) ----
    float s2A = dot16(a, a); s2A += __shfl_xor(s2A, 16);
    float s2B = dot16(b, b); s2B += __shfl_xor(s2B, 16);
    const float invA = __builtin_amdgcn_rsqf(fmaxf(s2A, 1e-30f));
    const float invB = __builtin_amdgcn_rsqf(fmaxf(s2B, 1e-30f));
    const float fvA = 0.5f * logf(fmaxf(s2A, 1e-38f));
    const float fvB = 0.5f * logf(fmaxf(s2B, 1e-38f));

    {
        // ||log M||_F^2 = sum_c f_c^2 (U orthogonal to ~1e-5)
        float sq = fvA * fvA + fvB * fvB;    // h=0 and h=1 rows both hold it
#pragma unroll
        for (int off = 1; off < 16; off <<= 1) sq += __shfl_xor(sq, off);
        if ((lane & 31) == 0) ssq[m0 + mw] = sq;
    }

    // ---- reconstruction: out = U f(S) U^T, ONE matrix per pass per wave ----
    const int c  = lane & 31;            // output column
    const int hh = lane >> 5;            // output row-half
    float* Uw = &Uld[wv][0];
    float* fw = &fld[wv][0];
#pragma unroll 1
    for (int p = 0; p < 2; ++p) {
        __syncthreads();   // Uld reuse between passes
        if (mw == p) {
#pragma unroll
            for (int j = 0; j < 8; ++j) {
                const int rA = r0 + 2 * j, rB = rA + 1;
                Uw[rA * 36 + cA] = a[j].x * invA;
                Uw[rB * 36 + cA] = a[j].y * invA;
                Uw[rA * 36 + cB] = b[j].x * invB;
                Uw[rB * 36 + cB] = b[j].y * invB;
            }
            if (h == 0) { fw[cA] = fvA; fw[cB] = fvB; }
        }
        __syncthreads();
        float rr[32];                    // rr[m] = f[m] * U[c][m]
        {
            const float4* urow = (const float4*)&Uw[c * 36];
            const float4* frow = (const float4*)&fw[0];
#pragma unroll
            for (int m4 = 0; m4 < 8; ++m4) {
                float4 u4 = urow[m4];
                float4 f4 = frow[m4];
                rr[m4 * 4 + 0] = u4.x * f4.x;
                rr[m4 * 4 + 1] = u4.y * f4.y;
                rr[m4 * 4 + 2] = u4.z * f4.z;
                rr[m4 * 4 + 3] = u4.w * f4.w;
            }
        }
        float* dst = out + (m0 + p) * 1024;
#pragma unroll
        for (int i = 0; i < 16; ++i) {
            const int row = hh * 16 + i;
            float acc = 0.f;
            const float4* urow = (const float4*)&Uw[row * 36];  // broadcast
#pragma unroll
            for (int m4 = 0; m4 < 8; ++m4) {
                float4 u4 = urow[m4];
                acc = fmaf(u4.x, rr[m4 * 4 + 0], acc);
                acc = fmaf(u4.y, rr[m4 * 4 + 1], acc);
                acc = fmaf(u4.z, rr[m4 * 4 + 2], acc);
                acc = fmaf(u4.w, rr[m4 * 4 + 3], acc);
            }
            dst[row * 32 + c] = acc;     // coalesced per half-wave
        }
    }
}

// ---------------------------------------------------------------------------
// K5: expm via scaling-and-squaring (R13 structure, unchanged — ~125 us).
// expm(S) = (Taylor8(S/32))^(2^5); spectrum of S in [-13, 2.6].
// ---------------------------------------------------------------------------
__global__ __launch_bounds__(256) void expm_kernel(
    const float* __restrict__ S, float* __restrict__ out)
{
    __shared__ __align__(16) float Xb[4][32 * 36];
    __shared__ __align__(16) float Pb[4][32 * 36];
    const int tid  = threadIdx.x;
    const int mat  = tid >> 6;           // matrix slot (wave) in block
    const int lane = tid & 63;
    const int c    = lane & 31;          // owned output column
    const int h    = lane >> 5;          // row-half
    const int r0   = h * 16;
    const size_t midx = (size_t)blockIdx.x * 4 + mat;

    // load 4 matrices, scaled by 1/32 (coalesced float4)
    {
        const float* sb = S + (size_t)blockIdx.x * 4096;
#pragma unroll
        for (int it = 0; it < 4; ++it) {
            const int f   = tid * 4 + it * 1024;   // 0..4095
            const int m   = f >> 10;
            const int off = f & 1023;
            const int r   = off >> 5;
            const int c0  = off & 31;
            float4 g = *(const float4*)&sb[f];
            g.x *= 0.03125f; g.y *= 0.03125f; g.z *= 0.03125f; g.w *= 0.03125f;
            *(float4*)&Xb[m][r * 36 + c0] = g;
        }
    }
    __syncthreads();

    // seed: P = X/8 + I
#pragma unroll
    for (int i = 0; i < 16; ++i) {
        const int r = r0 + i;
        Pb[mat][r * 36 + c] =
            Xb[mat][r * 36 + c] * 0.125f + ((r == c) ? 1.f : 0.f);
    }
    __syncthreads();

    // Horner d = 7..1 : P <- (X*P)/d + I
#pragma unroll 1
    for (int d = 7; d >= 1; --d) {
        const float invd = __builtin_amdgcn_rcpf((float)d);
        float p[32];
#pragma unroll
        for (int k = 0; k < 32; ++k) p[k] = Pb[mat][k * 36 + c];
        float acc[16];
#pragma unroll
        for (int i = 0; i < 16; ++i) {
            const int r = r0 + i;
            const float4* row = (const float4*)&Xb[mat][r * 36];   // broadcast
            float s0 = 0.f, s1 = 0.f;
#pragma unroll
            for (int m4 = 0; m4 < 8; m4 += 2) {
                const float4 u = row[m4];
                const float4 v = row[m4 + 1];
                s0 = fmaf(u.x, p[4 * m4 + 0], s0);
                s0 = fmaf(u.y, p[4 * m4 + 1], s0);
                s0 = fmaf(u.z, p[4 * m4 + 2], s0);
                s0 = fmaf(u.w, p[4 * m4 + 3], s0);
                s1 = fmaf(v.x, p[4 * m4 + 4], s1);
                s1 = fmaf(v.y, p[4 * m4 + 5], s1);
                s1 = fmaf(v.z, p[4 * m4 + 6], s1);
                s1 = fmaf(v.w, p[4 * m4 + 7], s1);
            }
            acc[i] = fmaf(s0 + s1, invd, (r == c) ? 1.f : 0.f);
        }
        __syncthreads();
#pragma unroll
        for (int i = 0; i < 16; ++i) Pb[mat][(r0 + i) * 36 + c] = acc[i];
        __syncthreads();
    }

    // 5 squarings: P <- P*P ; final result goes straight to global
#pragma unroll 1
    for (int t5 = 0; t5 < 5; ++t5) {
        float p[32];
#pragma unroll
        for (int k = 0; k < 32; ++k) p[k] = Pb[mat][k * 36 + c];
        float acc[16];
#pragma unroll
        for (int i = 0; i < 16; ++i) {
            const int r = r0 + i;
            const float4* row = (const float4*)&Pb[mat][r * 36];   // broadcast
            float s0 = 0.f, s1 = 0.f;
#pragma unroll
            for (int m4 = 0; m4 < 8; m4 += 2) {
                const float4 u = row[m4];
                const float4 v = row[m4 + 1];
                s0 = fmaf(u.x, p[4 * m4 + 0], s0);
                s0 = fmaf(u.y, p[4 * m4 + 1], s0);
                s0 = fmaf(u.z, p[4 * m4 + 2], s0);
                s0 = fmaf(u.w, p[4 * m4 + 3], s0);
                s1 = fmaf(v.x, p[4 * m4 + 4], s1);
                s1 = fmaf(v.y, p[4 * m4 + 5], s1);
                s1 = fmaf(v.z, p[4 * m4 + 6], s1);
                s1 = fmaf(v.w, p[4 * m4 + 7], s1);
            }
            acc[i] = s0 + s1;
        }
        if (t5 < 4) {
            __syncthreads();
#pragma unroll
            for (int i = 0; i < 16; ++i) Pb[mat][(r0 + i) * 36 + c] = acc[i];
            __syncthreads();
        } else {
            float* dst = out + midx * 1024;
#pragma unroll
            for (int i = 0; i < 16; ++i)
                dst[(r0 + i) * 32 + c] = acc[i];     // coalesced per half-wave
        }
    }
}

// ---------------------------------------------------------------------------
// K3a: weights[b,q,k] = 1/(1+log1p(max(qq+kk-2*<LQ_q,LK_k>_F, 0)))
// ---------------------------------------------------------------------------
__global__ __launch_bounds__(256) void qk_weights_kernel(
    const float* __restrict__ L, const float* __restrict__ ssq,
    float* __restrict__ wbuf)
{
    __shared__ float Aq[32 * 37];
    __shared__ float Bk[32 * 37];
    const int b  = blockIdx.z;
    const int q0 = blockIdx.y * 32;
    const int k0 = blockIdx.x * 32;
    const int tid = threadIdx.x;
    const int tx = tid & 15, ty = tid >> 4;
    const float* LQ = L + ((size_t)b * 128 + q0) * 1024;
    const float* LK = L + (size_t)NM * 1024 + ((size_t)b * 128 + k0) * 1024;
    const int lrow = tid >> 3;
    const int lm4  = (tid & 7) * 4;
    float acc00 = 0, acc01 = 0, acc10 = 0, acc11 = 0;
    for (int m0 = 0; m0 < 1024; m0 += 32) {
        __syncthreads();
        float4 va = *(const float4*)&LQ[(size_t)lrow * 1024 + m0 + lm4];
        float4 vb = *(const float4*)&LK[(size_t)lrow * 1024 + m0 + lm4];
        Aq[lrow * 37 + lm4 + 0] = va.x; Aq[lrow * 37 + lm4 + 1] = va.y;
        Aq[lrow * 37 + lm4 + 2] = va.z; Aq[lrow * 37 + lm4 + 3] = va.w;
        Bk[lrow * 37 + lm4 + 0] = vb.x; Bk[lrow * 37 + lm4 + 1] = vb.y;
        Bk[lrow * 37 + lm4 + 2] = vb.z; Bk[lrow * 37 + lm4 + 3] = vb.w;
        __syncthreads();
#pragma unroll
        for (int mm = 0; mm < 32; ++mm) {
            float a0 = Aq[(ty * 2 + 0) * 37 + mm];
            float a1 = Aq[(ty * 2 + 1) * 37 + mm];
            float b0 = Bk[(tx * 2 + 0) * 37 + mm];
            float b1 = Bk[(tx * 2 + 1) * 37 + mm];
            acc00 = fmaf(a0, b0, acc00); acc01 = fmaf(a0, b1, acc01);
            acc10 = fmaf(a1, b0, acc10); acc11 = fmaf(a1, b1, acc11);
        }
    }
    const float* qqp = ssq + (size_t)b * 128 + q0;
    const float* kkp = ssq + NM + (size_t)b * 128 + k0;
    const int q = ty * 2, k = tx * 2;
    float* wrow0 = wbuf + ((size_t)b * 128 + q0 + q) * 128 + k0 + k;
    float* wrow1 = wrow0 + 128;
    float e;
    e = fmaxf(qqp[q] + kkp[k] - 2.0f * acc00, 0.0f);
    wrow0[0] = 1.0f / (1.0f + log1pf(e));
    e = fmaxf(qqp[q] + kkp[k + 1] - 2.0f * acc01, 0.0f);
    wrow0[1] = 1.0f / (1.0f + log1pf(e));
    e = fmaxf(qqp[q + 1] + kkp[k] - 2.0f * acc10, 0.0f);
    wrow1[0] = 1.0f / (1.0f + log1pf(e));
    e = fmaxf(qqp[q + 1] + kkp[k + 1] - 2.0f * acc11, 0.0f);
    wrow1[1] = 1.0f / (1.0f + log1pf(e));
}

// ---------------------------------------------------------------------------
// K3b: in-place softmax over the QUERY axis (column-wise on [q][k])
// ---------------------------------------------------------------------------
__global__ __launch_bounds__(256) void softmax_kernel(float* __restrict__ wbuf)
{
    __shared__ float crcp[128];
    const int t = threadIdx.x;
    float* wb = wbuf + (size_t)blockIdx.x * 16384;
    if (t < 128) {
        float ssum = 0.f;
        for (int q = 0; q < 128; ++q) ssum += expf(wb[q * 128 + t]);
        crcp[t] = 1.0f / ssum;
    }
    __syncthreads();
    for (int i = t; i < 16384; i += 256)
        wb[i] = expf(wb[i]) * crcp[i & 127];
}

// ---------------------------------------------------------------------------
// K4: mean_log[b,i,:] = sum_j soft[b,j,i] * LV[b,j,:]
// ---------------------------------------------------------------------------
__global__ __launch_bounds__(256) void meanlog_kernel(
    const float* __restrict__ soft, const float* __restrict__ LV,
    float* __restrict__ ML)
{
    __shared__ float Wt[32 * 129];
    __shared__ __align__(16) float Bl[32 * 260];
    const int b  = blockIdx.z;
    const int i0 = blockIdx.y * 32;
    const int c0 = blockIdx.x * 256;
    const int t  = threadIdx.x;
    const float* sp = soft + (size_t)b * 16384;
#pragma unroll
    for (int jb = 0; jb < 4; ++jb) {
        int j  = jb * 32 + (t >> 3);
        int i4 = (t & 7) * 4;
        float4 v = *(const float4*)&sp[(size_t)j * 128 + i0 + i4];
        Wt[(i4 + 0) * 129 + j] = v.x;
        Wt[(i4 + 1) * 129 + j] = v.y;
        Wt[(i4 + 2) * 129 + j] = v.z;
        Wt[(i4 + 3) * 129 + j] = v.w;
    }
    float acc[32];
#pragma unroll
    for (int i = 0; i < 32; ++i) acc[i] = 0.f;
    const float* lv = LV + (size_t)2 * NM * 1024 + (size_t)b * 128 * 1024 + c0;
    for (int j0 = 0; j0 < 128; j0 += 32) {
        __syncthreads();
#pragma unroll
        for (int jj8 = 0; jj8 < 8; ++jj8) {
            int j  = jj8 * 4 + (t >> 6);
            int c4 = (t & 63) * 4;
            *(float4*)&Bl[j * 260 + c4] =
                *(const float4*)&lv[(size_t)(j0 + j) * 1024 + c4];
        }
        __syncthreads();
#pragma unroll
        for (int jj = 0; jj < 32; ++jj) {
            float v = Bl[jj * 260 + t];
#pragma unroll
            for (int i = 0; i < 32; ++i)
                acc[i] = fmaf(Wt[i * 129 + j0 + jj], v, acc[i]);
        }
    }
    float* mp = ML + ((size_t)b * 128 + i0) * 1024 + c0;
#pragma unroll
    for (int i = 0; i < 32; ++i) mp[(size_t)i * 1024 + t] = acc[i];
}

// ---------------------------------------------------------------------------
// launcher
// ---------------------------------------------------------------------------
extern "C" void kernel_launch(void* const* d_in, const int* in_sizes, int n_in,
                              void* d_out, int out_size, void* d_ws, size_t ws_size,
                              hipStream_t stream)
{
    const float* x  = (const float*)d_in[0];
    const float* Wq = (const float*)d_in[1];
    const float* Wk = (const float*)d_in[2];
    const float* Wv = (const float*)d_in[3];
    float* ws   = (float*)d_ws;
    float* qkv  = ws;                               // 3*NM*1024
    float* ssqp = ws + (size_t)3 * NM * 1024;       // 12288 (padded 16384)
    float* wbuf = ssqp + 16384;                     // NM*128
    float* out  = (float*)d_out;

    bimap_kernel<<<NM, 256, 0, stream>>>(x, Wq, Wk, Wv, qkv);
    log_eig_kernel<<<NMAT3 / 8, 256, 0, stream>>>(qkv, qkv, ssqp);
    qk_weights_kernel<<<dim3(4, 4, 32), 256, 0, stream>>>(qkv, ssqp, wbuf);
    softmax_kernel<<<32, 256, 0, stream>>>(wbuf);
    meanlog_kernel<<<dim3(4, 4, 32), 256, 0, stream>>>(wbuf, qkv, qkv);
    expm_kernel<<<NM / 4, 256, 0, stream>>>(qkv, out);
}

// Round 15
// 785.043 us; speedup vs baseline: 1.0255x; 1.0255x over previous
//
#include <hip/hip_runtime.h>
#include <math.h>

// Problem constants
#define NB   32
#define NP   128
#define NM   4096        // NB*NP matrices per type
#define NMAT3 12288      // 3*NM (Q,K,V)

typedef float v2f __attribute__((ext_vector_type(2)));

__device__ __forceinline__ v2f v2fma(v2f x, v2f y, v2f z) {
#if defined(__has_builtin)
#if __has_builtin(__builtin_elementwise_fma)
    return __builtin_elementwise_fma(x, y, z);
#else
    return (v2f){fmaf(x.x, y.x, z.x), fmaf(x.y, y.y, z.y)};
#endif
#else
    return (v2f){fmaf(x.x, y.x, z.x), fmaf(x.y, y.y, z.y)};
#endif
}

// ---------------------------------------------------------------------------
// K1: bimap — Q/K/V[b,p] = W * x[b,p] * W^T   (x: 64x64 SPD, W: 32x64)
// ---------------------------------------------------------------------------
__global__ __launch_bounds__(256) void bimap_kernel(
    const float* __restrict__ x, const float* __restrict__ Wq,
    const float* __restrict__ Wk, const float* __restrict__ Wv,
    float* __restrict__ qkv)
{
    __shared__ __align__(16) float S[64 * 64];
    __shared__ float Wl[32 * 65];
    __shared__ float T[32 * 65];
    const int tid = threadIdx.x;
    const int bp  = blockIdx.x;
    const float* xs = x + (size_t)bp * 4096;
#pragma unroll
    for (int k = 0; k < 4; ++k) {
        int idx = tid * 4 + k * 1024;
        *(float4*)&S[idx] = *(const float4*)&xs[idx];
    }
    const int o32 = tid & 31;
    const int grp = tid >> 5;
#pragma unroll 1
    for (int w = 0; w < 3; ++w) {
        const float* Wsrc = (w == 0) ? Wq : ((w == 1) ? Wk : Wv);
        __syncthreads();
#pragma unroll
        for (int k = 0; k < 8; ++k) {
            int f = tid + k * 256;
            Wl[(f >> 6) * 65 + (f & 63)] = Wsrc[f];
        }
        __syncthreads();
        {
            float acc[8];
#pragma unroll
            for (int jj = 0; jj < 8; ++jj) acc[jj] = 0.f;
            const int j0 = grp * 8;
#pragma unroll 4
            for (int i = 0; i < 64; ++i) {
                float wv = Wl[o32 * 65 + i];
                const float4 s0 = *(const float4*)&S[i * 64 + j0];
                const float4 s1 = *(const float4*)&S[i * 64 + j0 + 4];
                acc[0] = fmaf(wv, s0.x, acc[0]);
                acc[1] = fmaf(wv, s0.y, acc[1]);
                acc[2] = fmaf(wv, s0.z, acc[2]);
                acc[3] = fmaf(wv, s0.w, acc[3]);
                acc[4] = fmaf(wv, s1.x, acc[4]);
                acc[5] = fmaf(wv, s1.y, acc[5]);
                acc[6] = fmaf(wv, s1.z, acc[6]);
                acc[7] = fmaf(wv, s1.w, acc[7]);
            }
#pragma unroll
            for (int jj = 0; jj < 8; ++jj) T[o32 * 65 + j0 + jj] = acc[jj];
        }
        __syncthreads();
        {
            float oacc[4] = {0.f, 0.f, 0.f, 0.f};
            const int kcol = tid & 31;
            const int ob   = grp * 4;
#pragma unroll 4
            for (int j = 0; j < 64; ++j) {
                float wv = Wl[kcol * 65 + j];
#pragma unroll
                for (int cc = 0; cc < 4; ++cc)
                    oacc[cc] = fmaf(T[(ob + cc) * 65 + j], wv, oacc[cc]);
            }
            float* dst = qkv + ((size_t)w * NM + bp) * 1024;
#pragma unroll
            for (int cc = 0; cc < 4; ++cc)
                dst[(ob + cc) * 32 + kcol] = oacc[cc];
        }
    }
}

// ---------------------------------------------------------------------------
// K2: batched logm via one-sided Jacobi, lane-per-pair systolic, half-column
// per lane (R13's 565us form; pk-asm reverted — R14 falsified scalarization).
//
// Sweep-break at 1e-4 (angle 1e-2), was 1e-7: quadratic convergence means a
// sweep that saw only angles <=1e-2 (all still rotated; rotation threshold
// 1e-10 unchanged) leaves residual ~theta^2 ~ 1e-4 angles; f(A) error per
// pair is <= cos/2 (max of cos*(ln r)*r/(r^2-1) over r) ~ 5e-5 — negligible.
// Removes the pure-confirm sweep (~12% of rounds).
// ---------------------------------------------------------------------------
__device__ __forceinline__ float ror1(float x) {   // dest i <- src (i-1)&15
    return __int_as_float(__builtin_amdgcn_mov_dpp(
        __float_as_int(x), 0x121, 0xf, 0xf, true));
}
__device__ __forceinline__ float ror15(float x) {  // dest i <- src (i+1)&15
    return __int_as_float(__builtin_amdgcn_mov_dpp(
        __float_as_int(x), 0x12F, 0xf, 0xf, true));
}

__device__ __forceinline__ float dot16(const v2f (&x)[8], const v2f (&y)[8]) {
    v2f g0 = {0.f, 0.f}, g1 = {0.f, 0.f};
#pragma unroll
    for (int j = 0; j < 8; j += 2) {
        g0 = v2fma(x[j], y[j], g0);
        g1 = v2fma(x[j + 1], y[j + 1], g1);
    }
    v2f g = g0 + g1;
    return g.x + g.y;
}

__device__ __forceinline__ void jupdate(v2f (&a)[8], v2f (&b)[8],
                                        float& alA, float& alB,
                                        float gm, bool doRot) {
    const float zeta = (alB - alA) * __builtin_amdgcn_rcpf(2.0f * gm);
    float tt = copysignf(__builtin_amdgcn_rcpf(
        fabsf(zeta) + __builtin_amdgcn_sqrtf(fmaf(zeta, zeta, 1.0f))), zeta);
    float cc = __builtin_amdgcn_rsqf(fmaf(tt, tt, 1.0f));
    float sn = cc * tt;
    if (!doRot) { cc = 1.0f; sn = 0.0f; }   // NaN-safe when gm==0
    const v2f c2 = {cc, cc}, spv = {sn, sn}, smv = {-sn, -sn};
#pragma unroll
    for (int j = 0; j < 8; ++j) {
        const v2f ao = a[j], bo = b[j];
        a[j] = v2fma(c2, ao, smv * bo);
        b[j] = v2fma(c2, bo, spv * ao);
    }
    const float cq = cc * cc, sq = sn * sn, cs2 = 2.0f * cc * sn * gm;
    const float nA = fmaf(cq, alA, fmaf(sq, alB, -cs2));
    const float nB = fmaf(sq, alA, fmaf(cq, alB, cs2));
    alA = nA; alB = nB;
}

__global__ __launch_bounds__(256) void log_eig_kernel(
    const float* in, float* out, float* __restrict__ ssq)
{
    __shared__ __align__(16) float Uld[4][32 * 36];   // per-wave slice
    __shared__ __align__(16) float fld[4][32];
    const int tid  = threadIdx.x;
    const int wv   = tid >> 6;           // wave in block (0..3)
    const int lane = tid & 63;
    const int idx  = lane & 15;          // pair slot within row
    const int h    = (lane >> 4) & 1;    // row-half of the matrix
    const int mw   = lane >> 5;          // matrix within wave (0/1)
    const bool l14 = (idx == 14), l15 = (idx == 15);
    const int cA = idx * 2, cB = idx * 2 + 1;   // initial owned columns
    const int r0 = h * 16;               // first row this lane holds
    const size_t m0 = (size_t)blockIdx.x * 8 + wv * 2;

    const float* src = in + (m0 + mw) * 1024;
    v2f a[8], b[8];
#pragma unroll
    for (int j = 0; j < 8; ++j) {
        const int rA = r0 + 2 * j, rB = rA + 1;
        float2 lo = *(const float2*)&src[rA * 32 + cA];   // (A[rA][cA], A[rA][cB])
        float2 hi = *(const float2*)&src[rB * 32 + cA];
        a[j] = (v2f){lo.x, hi.x};
        b[j] = (v2f){lo.y, hi.y};
    }

    // ---- Jacobi sweeps: 31 systolic rounds/sweep (all per-wave) ----
    for (int sweep = 0; sweep < 10; ++sweep) {
        float alA = dot16(a, a); alA += __shfl_xor(alA, 16);
        float alB = dot16(b, b); alB += __shfl_xor(alB, 16);
        bool bigrot = false;
        for (int r = 0; r < 31; ++r) {
            float gm = dot16(a, b);
            gm += __shfl_xor(gm, 16);
            const float t  = alA * alB;
            const float g2 = gm * gm;
            const bool doRot = g2 > 1e-10f * t;
            bigrot |= (g2 > 1e-4f * t);   // quadratic-convergence break (see hdr)
            if (__any((int)doRot))
                jupdate(a, b, alA, alB, gm, doRot);
            // ---- migrate (R5-verified circle schedule, per 16-lane row) ----
            {
                const float alAg = ror1(alA), alBg = ror15(alB), alAo = alA;
                alA = l15 ? alBg : alAg;
                alB = l15 ? alB : (l14 ? alAo : alBg);
            }
#pragma unroll
            for (int j = 0; j < 8; ++j) {
                const v2f ao = a[j], bo = b[j];
                v2f t2, an;
                t2.x = ror15(bo.x); t2.y = ror15(bo.y);
                an.x = ror1(ao.x);  an.y = ror1(ao.y);
                a[j] = l15 ? t2 : an;
                v2f bn = l14 ? ao : t2;
                b[j] = l15 ? bo : bn;
            }
        }
        if (!__any((int)bigrot)) break;   // sweep saw only sub-1e-2 angles
    }

    // ---- finals (each column's sigma; both halves identical) ----
    float s2A = dot16(a, a); s2A += __shfl_xor(s2A, 16);
    float s2B = dot16(b, b); s2B += __shfl_xor(s2B, 16);
    const float invA = __builtin_amdgcn_rsqf(fmaxf(s2A, 1e-30f));
    const float invB = __builtin_amdgcn_rsqf(fmaxf(s2B, 1e-30f));
    const float fvA = 0.5f * logf(fmaxf(s2A, 1e-38f));
    const float fvB = 0.5f * logf(fmaxf(s2B, 1e-38f));

    {
        // ||log M||_F^2 = sum_c f_c^2 (U orthogonal to ~1e-4)
        float sq = fvA * fvA + fvB * fvB;    // h=0 and h=1 rows both hold it
#pragma unroll
        for (int off = 1; off < 16; off <<= 1) sq += __shfl_xor(sq, off);
        if ((lane & 31) == 0) ssq[m0 + mw] = sq;
    }

    // ---- reconstruction: out = U f(S) U^T, ONE matrix per pass per wave ----
    const int c  = lane & 31;            // output column
    const int hh = lane >> 5;            // output row-half
    float* Uw = &Uld[wv][0];
    float* fw = &fld[wv][0];
#pragma unroll 1
    for (int p = 0; p < 2; ++p) {
        __syncthreads();   // Uld reuse between passes
        if (mw == p) {
#pragma unroll
            for (int j = 0; j < 8; ++j) {
                const int rA = r0 + 2 * j, rB = rA + 1;
                Uw[rA * 36 + cA] = a[j].x * invA;
                Uw[rB * 36 + cA] = a[j].y * invA;
                Uw[rA * 36 + cB] = b[j].x * invB;
                Uw[rB * 36 + cB] = b[j].y * invB;
            }
            if (h == 0) { fw[cA] = fvA; fw[cB] = fvB; }
        }
        __syncthreads();
        float rr[32];                    // rr[m] = f[m] * U[c][m]
        {
            const float4* urow = (const float4*)&Uw[c * 36];
            const float4* frow = (const float4*)&fw[0];
#pragma unroll
            for (int m4 = 0; m4 < 8; ++m4) {
                float4 u4 = urow[m4];
                float4 f4 = frow[m4];
                rr[m4 * 4 + 0] = u4.x * f4.x;
                rr[m4 * 4 + 1] = u4.y * f4.y;
                rr[m4 * 4 + 2] = u4.z * f4.z;
                rr[m4 * 4 + 3] = u4.w * f4.w;
            }
        }
        float* dst = out + (m0 + p) * 1024;
#pragma unroll
        for (int i = 0; i < 16; ++i) {
            const int row = hh * 16 + i;
            float acc = 0.f;
            const float4* urow = (const float4*)&Uw[row * 36];  // broadcast
#pragma unroll
            for (int m4 = 0; m4 < 8; ++m4) {
                float4 u4 = urow[m4];
                acc = fmaf(u4.x, rr[m4 * 4 + 0], acc);
                acc = fmaf(u4.y, rr[m4 * 4 + 1], acc);
                acc = fmaf(u4.z, rr[m4 * 4 + 2], acc);
                acc = fmaf(u4.w, rr[m4 * 4 + 3], acc);
            }
            dst[row * 32 + c] = acc;     // coalesced per half-wave
        }
    }
}

// ---------------------------------------------------------------------------
// K5: expm via scaling-and-squaring (R13 structure + two refinements).
// expm(S) = (Taylor6(S/64))^(2^6): ||S/64|| <= 0.21, truncation
// 0.21^7*e^0.21/7! ~ 3e-10 — 5 Horner + 6 squaring = 11 matmuls (was 12).
// SYMMETRY: every P here is a polynomial/power of X -> symmetric, and X*P
// symmetric (they commute). So column c == row c: the strided 32x b32
// column reads become 8x b128 row reads, and the 16x b32 write-back
// becomes 4x b128 — ~25% fewer DS instructions in a DS-bound kernel.
// ---------------------------------------------------------------------------
__global__ __launch_bounds__(256) void expm_kernel(
    const float* __restrict__ S, float* __restrict__ out)
{
    __shared__ __align__(16) float Xb[4][32 * 36];
    __shared__ __align__(16) float Pb[4][32 * 36];
    const int tid  = threadIdx.x;
    const int mat  = tid >> 6;           // matrix slot (wave) in block
    const int lane = tid & 63;
    const int c    = lane & 31;          // owned output column (== row, symm)
    const int h    = lane >> 5;          // row-half
    const int r0   = h * 16;
    const size_t midx = (size_t)blockIdx.x * 4 + mat;

    // load 4 matrices, scaled by 1/64 (coalesced float4)
    {
        const float* sb = S + (size_t)blockIdx.x * 4096;
#pragma unroll
        for (int it = 0; it < 4; ++it) {
            const int f   = tid * 4 + it * 1024;   // 0..4095
            const int m   = f >> 10;
            const int off = f & 1023;
            const int r   = off >> 5;
            const int c0  = off & 31;
            float4 g = *(const float4*)&sb[f];
            g.x *= 0.015625f; g.y *= 0.015625f; g.z *= 0.015625f; g.w *= 0.015625f;
            *(float4*)&Xb[m][r * 36 + c0] = g;
        }
    }
    __syncthreads();

    // seed: P = X/6 + I, written as row c (cols r0..r0+15), b128
    {
        const float inv6 = 1.0f / 6.0f;
#pragma unroll
        for (int q = 0; q < 4; ++q) {
            float4 g = *(const float4*)&Xb[mat][c * 36 + r0 + 4 * q];
            g.x = g.x * inv6 + ((c == r0 + 4 * q + 0) ? 1.f : 0.f);
            g.y = g.y * inv6 + ((c == r0 + 4 * q + 1) ? 1.f : 0.f);
            g.z = g.z * inv6 + ((c == r0 + 4 * q + 2) ? 1.f : 0.f);
            g.w = g.w * inv6 + ((c == r0 + 4 * q + 3) ? 1.f : 0.f);
            *(float4*)&Pb[mat][c * 36 + r0 + 4 * q] = g;
        }
    }
    __syncthreads();

    // Horner d = 5..1 : P <- (X*P)/d + I
#pragma unroll 1
    for (int d = 5; d >= 1; --d) {
        const float invd = __builtin_amdgcn_rcpf((float)d);
        float p[32];   // column c of P == row c (symmetric), 8x b128
        {
            const float4* prow = (const float4*)&Pb[mat][c * 36];
#pragma unroll
            for (int m4 = 0; m4 < 8; ++m4) {
                float4 g = prow[m4];
                p[4 * m4 + 0] = g.x; p[4 * m4 + 1] = g.y;
                p[4 * m4 + 2] = g.z; p[4 * m4 + 3] = g.w;
            }
        }
        float acc[16];
#pragma unroll
        for (int i = 0; i < 16; ++i) {
            const int r = r0 + i;
            const float4* row = (const float4*)&Xb[mat][r * 36];   // broadcast
            float s0 = 0.f, s1 = 0.f;
#pragma unroll
            for (int m4 = 0; m4 < 8; m4 += 2) {
                const float4 u = row[m4];
                const float4 v = row[m4 + 1];
                s0 = fmaf(u.x, p[4 * m4 + 0], s0);
                s0 = fmaf(u.y, p[4 * m4 + 1], s0);
                s0 = fmaf(u.z, p[4 * m4 + 2], s0);
                s0 = fmaf(u.w, p[4 * m4 + 3], s0);
                s1 = fmaf(v.x, p[4 * m4 + 4], s1);
                s1 = fmaf(v.y, p[4 * m4 + 5], s1);
                s1 = fmaf(v.z, p[4 * m4 + 6], s1);
                s1 = fmaf(v.w, p[4 * m4 + 7], s1);
            }
            acc[i] = fmaf(s0 + s1, invd, (r == c) ? 1.f : 0.f);
        }
        __syncthreads();
        // write back as row c (symmetric), 4x b128
#pragma unroll
        for (int q = 0; q < 4; ++q) {
            float4 g;
            g.x = acc[4 * q + 0]; g.y = acc[4 * q + 1];
            g.z = acc[4 * q + 2]; g.w = acc[4 * q + 3];
            *(float4*)&Pb[mat][c * 36 + r0 + 4 * q] = g;
        }
        __syncthreads();
    }

    // 6 squarings: P <- P*P ; final result goes straight to global
#pragma unroll 1
    for (int t5 = 0; t5 < 6; ++t5) {
        float p[32];
        {
            const float4* prow = (const float4*)&Pb[mat][c * 36];
#pragma unroll
            for (int m4 = 0; m4 < 8; ++m4) {
                float4 g = prow[m4];
                p[4 * m4 + 0] = g.x; p[4 * m4 + 1] = g.y;
                p[4 * m4 + 2] = g.z; p[4 * m4 + 3] = g.w;
            }
        }
        float acc[16];
#pragma unroll
        for (int i = 0; i < 16; ++i) {
            const int r = r0 + i;
            const float4* row = (const float4*)&Pb[mat][r * 36];   // broadcast
            float s0 = 0.f, s1 = 0.f;
#pragma unroll
            for (int m4 = 0; m4 < 8; m4 += 2) {
                const float4 u = row[m4];
                const float4 v = row[m4 + 1];
                s0 = fmaf(u.x, p[4 * m4 + 0], s0);
                s0 = fmaf(u.y, p[4 * m4 + 1], s0);
                s0 = fmaf(u.z, p[4 * m4 + 2], s0);
                s0 = fmaf(u.w, p[4 * m4 + 3], s0);
                s1 = fmaf(v.x, p[4 * m4 + 4], s1);
                s1 = fmaf(v.y, p[4 * m4 + 5], s1);
                s1 = fmaf(v.z, p[4 * m4 + 6], s1);
                s1 = fmaf(v.w, p[4 * m4 + 7], s1);
            }
            acc[i] = s0 + s1;
        }
        if (t5 < 5) {
            __syncthreads();
#pragma unroll
            for (int q = 0; q < 4; ++q) {
                float4 g;
                g.x = acc[4 * q + 0]; g.y = acc[4 * q + 1];
                g.z = acc[4 * q + 2]; g.w = acc[4 * q + 3];
                *(float4*)&Pb[mat][c * 36 + r0 + 4 * q] = g;
            }
            __syncthreads();
        } else {
            float* dst = out + midx * 1024;
#pragma unroll
            for (int i = 0; i < 16; ++i)
                dst[(r0 + i) * 32 + c] = acc[i];     // coalesced per half-wave
        }
    }
}

// ---------------------------------------------------------------------------
// K3a: weights[b,q,k] = 1/(1+log1p(max(qq+kk-2*<LQ_q,LK_k>_F, 0)))
// ---------------------------------------------------------------------------
__global__ __launch_bounds__(256) void qk_weights_kernel(
    const float* __restrict__ L, const float* __restrict__ ssq,
    float* __restrict__ wbuf)
{
    __shared__ float Aq[32 * 37];
    __shared__ float Bk[32 * 37];
    const int b  = blockIdx.z;
    const int q0 = blockIdx.y * 32;
    const int k0 = blockIdx.x * 32;
    const int tid = threadIdx.x;
    const int tx = tid & 15, ty = tid >> 4;
    const float* LQ = L + ((size_t)b * 128 + q0) * 1024;
    const float* LK = L + (size_t)NM * 1024 + ((size_t)b * 128 + k0) * 1024;
    const int lrow = tid >> 3;
    const int lm4  = (tid & 7) * 4;
    float acc00 = 0, acc01 = 0, acc10 = 0, acc11 = 0;
    for (int m0 = 0; m0 < 1024; m0 += 32) {
        __syncthreads();
        float4 va = *(const float4*)&LQ[(size_t)lrow * 1024 + m0 + lm4];
        float4 vb = *(const float4*)&LK[(size_t)lrow * 1024 + m0 + lm4];
        Aq[lrow * 37 + lm4 + 0] = va.x; Aq[lrow * 37 + lm4 + 1] = va.y;
        Aq[lrow * 37 + lm4 + 2] = va.z; Aq[lrow * 37 + lm4 + 3] = va.w;
        Bk[lrow * 37 + lm4 + 0] = vb.x; Bk[lrow * 37 + lm4 + 1] = vb.y;
        Bk[lrow * 37 + lm4 + 2] = vb.z; Bk[lrow * 37 + lm4 + 3] = vb.w;
        __syncthreads();
#pragma unroll
        for (int mm = 0; mm < 32; ++mm) {
            float a0 = Aq[(ty * 2 + 0) * 37 + mm];
            float a1 = Aq[(ty * 2 + 1) * 37 + mm];
            float b0 = Bk[(tx * 2 + 0) * 37 + mm];
            float b1 = Bk[(tx * 2 + 1) * 37 + mm];
            acc00 = fmaf(a0, b0, acc00); acc01 = fmaf(a0, b1, acc01);
            acc10 = fmaf(a1, b0, acc10); acc11 = fmaf(a1, b1, acc11);
        }
    }
    const float* qqp = ssq + (size_t)b * 128 + q0;
    const float* kkp = ssq + NM + (size_t)b * 128 + k0;
    const int q = ty * 2, k = tx * 2;
    float* wrow0 = wbuf + ((size_t)b * 128 + q0 + q) * 128 + k0 + k;
    float* wrow1 = wrow0 + 128;
    float e;
    e = fmaxf(qqp[q] + kkp[k] - 2.0f * acc00, 0.0f);
    wrow0[0] = 1.0f / (1.0f + log1pf(e));
    e = fmaxf(qqp[q] + kkp[k + 1] - 2.0f * acc01, 0.0f);
    wrow0[1] = 1.0f / (1.0f + log1pf(e));
    e = fmaxf(qqp[q + 1] + kkp[k] - 2.0f * acc10, 0.0f);
    wrow1[0] = 1.0f / (1.0f + log1pf(e));
    e = fmaxf(qqp[q + 1] + kkp[k + 1] - 2.0f * acc11, 0.0f);
    wrow1[1] = 1.0f / (1.0f + log1pf(e));
}

// ---------------------------------------------------------------------------
// K3b: in-place softmax over the QUERY axis (column-wise on [q][k])
// ---------------------------------------------------------------------------
__global__ __launch_bounds__(256) void softmax_kernel(float* __restrict__ wbuf)
{
    __shared__ float crcp[128];
    const int t = threadIdx.x;
    float* wb = wbuf + (size_t)blockIdx.x * 16384;
    if (t < 128) {
        float ssum = 0.f;
        for (int q = 0; q < 128; ++q) ssum += expf(wb[q * 128 + t]);
        crcp[t] = 1.0f / ssum;
    }
    __syncthreads();
    for (int i = t; i < 16384; i += 256)
        wb[i] = expf(wb[i]) * crcp[i & 127];
}

// ---------------------------------------------------------------------------
// K4: mean_log[b,i,:] = sum_j soft[b,j,i] * LV[b,j,:]
// ---------------------------------------------------------------------------
__global__ __launch_bounds__(256) void meanlog_kernel(
    const float* __restrict__ soft, const float* __restrict__ LV,
    float* __restrict__ ML)
{
    __shared__ float Wt[32 * 129];
    __shared__ __align__(16) float Bl[32 * 260];
    const int b  = blockIdx.z;
    const int i0 = blockIdx.y * 32;
    const int c0 = blockIdx.x * 256;
    const int t  = threadIdx.x;
    const float* sp = soft + (size_t)b * 16384;
#pragma unroll
    for (int jb = 0; jb < 4; ++jb) {
        int j  = jb * 32 + (t >> 3);
        int i4 = (t & 7) * 4;
        float4 v = *(const float4*)&sp[(size_t)j * 128 + i0 + i4];
        Wt[(i4 + 0) * 129 + j] = v.x;
        Wt[(i4 + 1) * 129 + j] = v.y;
        Wt[(i4 + 2) * 129 + j] = v.z;
        Wt[(i4 + 3) * 129 + j] = v.w;
    }
    float acc[32];
#pragma unroll
    for (int i = 0; i < 32; ++i) acc[i] = 0.f;
    const float* lv = LV + (size_t)2 * NM * 1024 + (size_t)b * 128 * 1024 + c0;
    for (int j0 = 0; j0 < 128; j0 += 32) {
        __syncthreads();
#pragma unroll
        for (int jj8 = 0; jj8 < 8; ++jj8) {
            int j  = jj8 * 4 + (t >> 6);
            int c4 = (t & 63) * 4;
            *(float4*)&Bl[j * 260 + c4] =
                *(const float4*)&lv[(size_t)(j0 + j) * 1024 + c4];
        }
        __syncthreads();
#pragma unroll
        for (int jj = 0; jj < 32; ++jj) {
            float v = Bl[jj * 260 + t];
#pragma unroll
            for (int i = 0; i < 32; ++i)
                acc[i] = fmaf(Wt[i * 129 + j0 + jj], v, acc[i]);
        }
    }
    float* mp = ML + ((size_t)b * 128 + i0) * 1024 + c0;
#pragma unroll
    for (int i = 0; i < 32; ++i) mp[(size_t)i * 1024 + t] = acc[i];
}

// ---------------------------------------------------------------------------
// launcher
// ---------------------------------------------------------------------------
extern "C" void kernel_launch(void* const* d_in, const int* in_sizes, int n_in,
                              void* d_out, int out_size, void* d_ws, size_t ws_size,
                              hipStream_t stream)
{
    const float* x  = (const float*)d_in[0];
    const float* Wq = (const float*)d_in[1];
    const float* Wk = (const float*)d_in[2];
    const float* Wv = (const float*)d_in[3];
    float* ws   = (float*)d_ws;
    float* qkv  = ws;                               // 3*NM*1024
    float* ssqp = ws + (size_t)3 * NM * 1024;       // 12288 (padded 16384)
    float* wbuf = ssqp + 16384;                     // NM*128
    float* out  = (float*)d_out;

    bimap_kernel<<<NM, 256, 0, stream>>>(x, Wq, Wk, Wv, qkv);
    log_eig_kernel<<<NMAT3 / 8, 256, 0, stream>>>(qkv, qkv, ssqp);
    qk_weights_kernel<<<dim3(4, 4, 32), 256, 0, stream>>>(qkv, ssqp, wbuf);
    softmax_kernel<<<32, 256, 0, stream>>>(wbuf);
    meanlog_kernel<<<dim3(4, 4, 32), 256, 0, stream>>>(wbuf, qkv, qkv);
    expm_kernel<<<NM / 4, 256, 0, stream>>>(qkv, out);
}

// Round 16
// 757.379 us; speedup vs baseline: 1.0630x; 1.0365x over previous
//
#include <hip/hip_runtime.h>
#include <math.h>

// Problem constants
#define NB   32
#define NP   128
#define NM   4096        // NB*NP matrices per type
#define NMAT3 12288      // 3*NM (Q,K,V)

typedef float v2f __attribute__((ext_vector_type(2)));

__device__ __forceinline__ v2f v2fma(v2f x, v2f y, v2f z) {
#if defined(__has_builtin)
#if __has_builtin(__builtin_elementwise_fma)
    return __builtin_elementwise_fma(x, y, z);
#else
    return (v2f){fmaf(x.x, y.x, z.x), fmaf(x.y, y.y, z.y)};
#endif
#else
    return (v2f){fmaf(x.x, y.x, z.x), fmaf(x.y, y.y, z.y)};
#endif
}

// ---------------------------------------------------------------------------
// K1: bimap — Q/K/V[b,p] = W * x[b,p] * W^T   (x: 64x64 SPD, W: 32x64)
// ---------------------------------------------------------------------------
__global__ __launch_bounds__(256) void bimap_kernel(
    const float* __restrict__ x, const float* __restrict__ Wq,
    const float* __restrict__ Wk, const float* __restrict__ Wv,
    float* __restrict__ qkv)
{
    __shared__ __align__(16) float S[64 * 64];
    __shared__ float Wl[32 * 65];
    __shared__ float T[32 * 65];
    const int tid = threadIdx.x;
    const int bp  = blockIdx.x;
    const float* xs = x + (size_t)bp * 4096;
#pragma unroll
    for (int k = 0; k < 4; ++k) {
        int idx = tid * 4 + k * 1024;
        *(float4*)&S[idx] = *(const float4*)&xs[idx];
    }
    const int o32 = tid & 31;
    const int grp = tid >> 5;
#pragma unroll 1
    for (int w = 0; w < 3; ++w) {
        const float* Wsrc = (w == 0) ? Wq : ((w == 1) ? Wk : Wv);
        __syncthreads();
#pragma unroll
        for (int k = 0; k < 8; ++k) {
            int f = tid + k * 256;
            Wl[(f >> 6) * 65 + (f & 63)] = Wsrc[f];
        }
        __syncthreads();
        {
            float acc[8];
#pragma unroll
            for (int jj = 0; jj < 8; ++jj) acc[jj] = 0.f;
            const int j0 = grp * 8;
#pragma unroll 4
            for (int i = 0; i < 64; ++i) {
                float wv = Wl[o32 * 65 + i];
                const float4 s0 = *(const float4*)&S[i * 64 + j0];
                const float4 s1 = *(const float4*)&S[i * 64 + j0 + 4];
                acc[0] = fmaf(wv, s0.x, acc[0]);
                acc[1] = fmaf(wv, s0.y, acc[1]);
                acc[2] = fmaf(wv, s0.z, acc[2]);
                acc[3] = fmaf(wv, s0.w, acc[3]);
                acc[4] = fmaf(wv, s1.x, acc[4]);
                acc[5] = fmaf(wv, s1.y, acc[5]);
                acc[6] = fmaf(wv, s1.z, acc[6]);
                acc[7] = fmaf(wv, s1.w, acc[7]);
            }
#pragma unroll
            for (int jj = 0; jj < 8; ++jj) T[o32 * 65 + j0 + jj] = acc[jj];
        }
        __syncthreads();
        {
            float oacc[4] = {0.f, 0.f, 0.f, 0.f};
            const int kcol = tid & 31;
            const int ob   = grp * 4;
#pragma unroll 4
            for (int j = 0; j < 64; ++j) {
                float wv = Wl[kcol * 65 + j];
#pragma unroll
                for (int cc = 0; cc < 4; ++cc)
                    oacc[cc] = fmaf(T[(ob + cc) * 65 + j], wv, oacc[cc]);
            }
            float* dst = qkv + ((size_t)w * NM + bp) * 1024;
#pragma unroll
            for (int cc = 0; cc < 4; ++cc)
                dst[(ob + cc) * 32 + kcol] = oacc[cc];
        }
    }
}

// ---------------------------------------------------------------------------
// K2: batched logm via one-sided Jacobi, lane-per-pair systolic, half-column
// per lane. 1e-4 sweep-break (R15-verified). At 90% VALUBusy / 0 conflicts /
// 0 spills with minimal per-pair update count — near its VALU roofline.
// ---------------------------------------------------------------------------
__device__ __forceinline__ float ror1(float x) {   // dest i <- src (i-1)&15
    return __int_as_float(__builtin_amdgcn_mov_dpp(
        __float_as_int(x), 0x121, 0xf, 0xf, true));
}
__device__ __forceinline__ float ror15(float x) {  // dest i <- src (i+1)&15
    return __int_as_float(__builtin_amdgcn_mov_dpp(
        __float_as_int(x), 0x12F, 0xf, 0xf, true));
}

__device__ __forceinline__ float dot16(const v2f (&x)[8], const v2f (&y)[8]) {
    v2f g0 = {0.f, 0.f}, g1 = {0.f, 0.f};
#pragma unroll
    for (int j = 0; j < 8; j += 2) {
        g0 = v2fma(x[j], y[j], g0);
        g1 = v2fma(x[j + 1], y[j + 1], g1);
    }
    v2f g = g0 + g1;
    return g.x + g.y;
}

__device__ __forceinline__ void jupdate(v2f (&a)[8], v2f (&b)[8],
                                        float& alA, float& alB,
                                        float gm, bool doRot) {
    const float zeta = (alB - alA) * __builtin_amdgcn_rcpf(2.0f * gm);
    float tt = copysignf(__builtin_amdgcn_rcpf(
        fabsf(zeta) + __builtin_amdgcn_sqrtf(fmaf(zeta, zeta, 1.0f))), zeta);
    float cc = __builtin_amdgcn_rsqf(fmaf(tt, tt, 1.0f));
    float sn = cc * tt;
    if (!doRot) { cc = 1.0f; sn = 0.0f; }   // NaN-safe when gm==0
    const v2f c2 = {cc, cc}, spv = {sn, sn}, smv = {-sn, -sn};
#pragma unroll
    for (int j = 0; j < 8; ++j) {
        const v2f ao = a[j], bo = b[j];
        a[j] = v2fma(c2, ao, smv * bo);
        b[j] = v2fma(c2, bo, spv * ao);
    }
    const float cq = cc * cc, sq = sn * sn, cs2 = 2.0f * cc * sn * gm;
    const float nA = fmaf(cq, alA, fmaf(sq, alB, -cs2));
    const float nB = fmaf(sq, alA, fmaf(cq, alB, cs2));
    alA = nA; alB = nB;
}

__global__ __launch_bounds__(256) void log_eig_kernel(
    const float* in, float* out, float* __restrict__ ssq)
{
    __shared__ __align__(16) float Uld[4][32 * 36];   // per-wave slice
    __shared__ __align__(16) float fld[4][32];
    const int tid  = threadIdx.x;
    const int wv   = tid >> 6;           // wave in block (0..3)
    const int lane = tid & 63;
    const int idx  = lane & 15;          // pair slot within row
    const int h    = (lane >> 4) & 1;    // row-half of the matrix
    const int mw   = lane >> 5;          // matrix within wave (0/1)
    const bool l14 = (idx == 14), l15 = (idx == 15);
    const int cA = idx * 2, cB = idx * 2 + 1;   // initial owned columns
    const int r0 = h * 16;               // first row this lane holds
    const size_t m0 = (size_t)blockIdx.x * 8 + wv * 2;

    const float* src = in + (m0 + mw) * 1024;
    v2f a[8], b[8];
#pragma unroll
    for (int j = 0; j < 8; ++j) {
        const int rA = r0 + 2 * j, rB = rA + 1;
        float2 lo = *(const float2*)&src[rA * 32 + cA];   // (A[rA][cA], A[rA][cB])
        float2 hi = *(const float2*)&src[rB * 32 + cA];
        a[j] = (v2f){lo.x, hi.x};
        b[j] = (v2f){lo.y, hi.y};
    }

    // ---- Jacobi sweeps: 31 systolic rounds/sweep (all per-wave) ----
    for (int sweep = 0; sweep < 10; ++sweep) {
        float alA = dot16(a, a); alA += __shfl_xor(alA, 16);
        float alB = dot16(b, b); alB += __shfl_xor(alB, 16);
        bool bigrot = false;
        for (int r = 0; r < 31; ++r) {
            float gm = dot16(a, b);
            gm += __shfl_xor(gm, 16);
            const float t  = alA * alB;
            const float g2 = gm * gm;
            const bool doRot = g2 > 1e-10f * t;
            bigrot |= (g2 > 1e-4f * t);   // quadratic-convergence break
            if (__any((int)doRot))
                jupdate(a, b, alA, alB, gm, doRot);
            // ---- migrate (R5-verified circle schedule, per 16-lane row) ----
            {
                const float alAg = ror1(alA), alBg = ror15(alB), alAo = alA;
                alA = l15 ? alBg : alAg;
                alB = l15 ? alB : (l14 ? alAo : alBg);
            }
#pragma unroll
            for (int j = 0; j < 8; ++j) {
                const v2f ao = a[j], bo = b[j];
                v2f t2, an;
                t2.x = ror15(bo.x); t2.y = ror15(bo.y);
                an.x = ror1(ao.x);  an.y = ror1(ao.y);
                a[j] = l15 ? t2 : an;
                v2f bn = l14 ? ao : t2;
                b[j] = l15 ? bo : bn;
            }
        }
        if (!__any((int)bigrot)) break;   // sweep saw only sub-1e-2 angles
    }

    // ---- finals (each column's sigma; both halves identical) ----
    float s2A = dot16(a, a); s2A += __shfl_xor(s2A, 16);
    float s2B = dot16(b, b); s2B += __shfl_xor(s2B, 16);
    const float invA = __builtin_amdgcn_rsqf(fmaxf(s2A, 1e-30f));
    const float invB = __builtin_amdgcn_rsqf(fmaxf(s2B, 1e-30f));
    const float fvA = 0.5f * logf(fmaxf(s2A, 1e-38f));
    const float fvB = 0.5f * logf(fmaxf(s2B, 1e-38f));

    {
        // ||log M||_F^2 = sum_c f_c^2 (U orthogonal to ~1e-4)
        float sq = fvA * fvA + fvB * fvB;    // h=0 and h=1 rows both hold it
#pragma unroll
        for (int off = 1; off < 16; off <<= 1) sq += __shfl_xor(sq, off);
        if ((lane & 31) == 0) ssq[m0 + mw] = sq;
    }

    // ---- reconstruction: out = U f(S) U^T, ONE matrix per pass per wave ----
    const int c  = lane & 31;            // output column
    const int hh = lane >> 5;            // output row-half
    float* Uw = &Uld[wv][0];
    float* fw = &fld[wv][0];
#pragma unroll 1
    for (int p = 0; p < 2; ++p) {
        __syncthreads();   // Uld reuse between passes
        if (mw == p) {
#pragma unroll
            for (int j = 0; j < 8; ++j) {
                const int rA = r0 + 2 * j, rB = rA + 1;
                Uw[rA * 36 + cA] = a[j].x * invA;
                Uw[rB * 36 + cA] = a[j].y * invA;
                Uw[rA * 36 + cB] = b[j].x * invB;
                Uw[rB * 36 + cB] = b[j].y * invB;
            }
            if (h == 0) { fw[cA] = fvA; fw[cB] = fvB; }
        }
        __syncthreads();
        float rr[32];                    // rr[m] = f[m] * U[c][m]
        {
            const float4* urow = (const float4*)&Uw[c * 36];
            const float4* frow = (const float4*)&fw[0];
#pragma unroll
            for (int m4 = 0; m4 < 8; ++m4) {
                float4 u4 = urow[m4];
                float4 f4 = frow[m4];
                rr[m4 * 4 + 0] = u4.x * f4.x;
                rr[m4 * 4 + 1] = u4.y * f4.y;
                rr[m4 * 4 + 2] = u4.z * f4.z;
                rr[m4 * 4 + 3] = u4.w * f4.w;
            }
        }
        float* dst = out + (m0 + p) * 1024;
#pragma unroll
        for (int i = 0; i < 16; ++i) {
            const int row = hh * 16 + i;
            float acc = 0.f;
            const float4* urow = (const float4*)&Uw[row * 36];  // broadcast
#pragma unroll
            for (int m4 = 0; m4 < 8; ++m4) {
                float4 u4 = urow[m4];
                acc = fmaf(u4.x, rr[m4 * 4 + 0], acc);
                acc = fmaf(u4.y, rr[m4 * 4 + 1], acc);
                acc = fmaf(u4.z, rr[m4 * 4 + 2], acc);
                acc = fmaf(u4.w, rr[m4 * 4 + 3], acc);
            }
            dst[row * 32 + c] = acc;     // coalesced per half-wave
        }
    }
}

// ---------------------------------------------------------------------------
// K5: expm via scaling-and-squaring. deg-6 @ s=64 (11 matmuls, R15-kept)
// with R13's CONFLICT-FREE access pattern restored (R15's symmetric b128
// row-read collided 4-way: bank = 4c mod 32 repeats every 8 lanes).
// Column read of P: 32x b32 at stride 36 -> bank (4k+c)%32, distinct across
// lanes for each k — conflict-free. X row reads: broadcast float4 (free).
// ---------------------------------------------------------------------------
__global__ __launch_bounds__(256) void expm_kernel(
    const float* __restrict__ S, float* __restrict__ out)
{
    __shared__ __align__(16) float Xb[4][32 * 36];
    __shared__ __align__(16) float Pb[4][32 * 36];
    const int tid  = threadIdx.x;
    const int mat  = tid >> 6;           // matrix slot (wave) in block
    const int lane = tid & 63;
    const int c    = lane & 31;          // owned output column
    const int h    = lane >> 5;          // row-half
    const int r0   = h * 16;
    const size_t midx = (size_t)blockIdx.x * 4 + mat;

    // load 4 matrices, scaled by 1/64 (coalesced float4)
    {
        const float* sb = S + (size_t)blockIdx.x * 4096;
#pragma unroll
        for (int it = 0; it < 4; ++it) {
            const int f   = tid * 4 + it * 1024;   // 0..4095
            const int m   = f >> 10;
            const int off = f & 1023;
            const int r   = off >> 5;
            const int c0  = off & 31;
            float4 g = *(const float4*)&sb[f];
            g.x *= 0.015625f; g.y *= 0.015625f; g.z *= 0.015625f; g.w *= 0.015625f;
            *(float4*)&Xb[m][r * 36 + c0] = g;
        }
    }
    __syncthreads();

    // seed: P = X/6 + I
    {
        const float inv6 = 1.0f / 6.0f;
#pragma unroll
        for (int i = 0; i < 16; ++i) {
            const int r = r0 + i;
            Pb[mat][r * 36 + c] =
                Xb[mat][r * 36 + c] * inv6 + ((r == c) ? 1.f : 0.f);
        }
    }
    __syncthreads();

    // Horner d = 5..1 : P <- (X*P)/d + I
#pragma unroll 1
    for (int d = 5; d >= 1; --d) {
        const float invd = __builtin_amdgcn_rcpf((float)d);
        float p[32];
#pragma unroll
        for (int k = 0; k < 32; ++k) p[k] = Pb[mat][k * 36 + c];
        float acc[16];
#pragma unroll
        for (int i = 0; i < 16; ++i) {
            const int r = r0 + i;
            const float4* row = (const float4*)&Xb[mat][r * 36];   // broadcast
            float s0 = 0.f, s1 = 0.f;
#pragma unroll
            for (int m4 = 0; m4 < 8; m4 += 2) {
                const float4 u = row[m4];
                const float4 v = row[m4 + 1];
                s0 = fmaf(u.x, p[4 * m4 + 0], s0);
                s0 = fmaf(u.y, p[4 * m4 + 1], s0);
                s0 = fmaf(u.z, p[4 * m4 + 2], s0);
                s0 = fmaf(u.w, p[4 * m4 + 3], s0);
                s1 = fmaf(v.x, p[4 * m4 + 4], s1);
                s1 = fmaf(v.y, p[4 * m4 + 5], s1);
                s1 = fmaf(v.z, p[4 * m4 + 6], s1);
                s1 = fmaf(v.w, p[4 * m4 + 7], s1);
            }
            acc[i] = fmaf(s0 + s1, invd, (r == c) ? 1.f : 0.f);
        }
        __syncthreads();
#pragma unroll
        for (int i = 0; i < 16; ++i) Pb[mat][(r0 + i) * 36 + c] = acc[i];
        __syncthreads();
    }

    // 6 squarings: P <- P*P ; final result goes straight to global
#pragma unroll 1
    for (int t5 = 0; t5 < 6; ++t5) {
        float p[32];
#pragma unroll
        for (int k = 0; k < 32; ++k) p[k] = Pb[mat][k * 36 + c];
        float acc[16];
#pragma unroll
        for (int i = 0; i < 16; ++i) {
            const int r = r0 + i;
            const float4* row = (const float4*)&Pb[mat][r * 36];   // broadcast
            float s0 = 0.f, s1 = 0.f;
#pragma unroll
            for (int m4 = 0; m4 < 8; m4 += 2) {
                const float4 u = row[m4];
                const float4 v = row[m4 + 1];
                s0 = fmaf(u.x, p[4 * m4 + 0], s0);
                s0 = fmaf(u.y, p[4 * m4 + 1], s0);
                s0 = fmaf(u.z, p[4 * m4 + 2], s0);
                s0 = fmaf(u.w, p[4 * m4 + 3], s0);
                s1 = fmaf(v.x, p[4 * m4 + 4], s1);
                s1 = fmaf(v.y, p[4 * m4 + 5], s1);
                s1 = fmaf(v.z, p[4 * m4 + 6], s1);
                s1 = fmaf(v.w, p[4 * m4 + 7], s1);
            }
            acc[i] = s0 + s1;
        }
        if (t5 < 5) {
            __syncthreads();
#pragma unroll
            for (int i = 0; i < 16; ++i) Pb[mat][(r0 + i) * 36 + c] = acc[i];
            __syncthreads();
        } else {
            float* dst = out + midx * 1024;
#pragma unroll
            for (int i = 0; i < 16; ++i)
                dst[(r0 + i) * 32 + c] = acc[i];     // coalesced per half-wave
        }
    }
}

// ---------------------------------------------------------------------------
// K3a: weights[b,q,k] = 1/(1+log1p(max(qq+kk-2*<LQ_q,LK_k>_F, 0)))
// ---------------------------------------------------------------------------
__global__ __launch_bounds__(256) void qk_weights_kernel(
    const float* __restrict__ L, const float* __restrict__ ssq,
    float* __restrict__ wbuf)
{
    __shared__ float Aq[32 * 37];
    __shared__ float Bk[32 * 37];
    const int b  = blockIdx.z;
    const int q0 = blockIdx.y * 32;
    const int k0 = blockIdx.x * 32;
    const int tid = threadIdx.x;
    const int tx = tid & 15, ty = tid >> 4;
    const float* LQ = L + ((size_t)b * 128 + q0) * 1024;
    const float* LK = L + (size_t)NM * 1024 + ((size_t)b * 128 + k0) * 1024;
    const int lrow = tid >> 3;
    const int lm4  = (tid & 7) * 4;
    float acc00 = 0, acc01 = 0, acc10 = 0, acc11 = 0;
    for (int m0 = 0; m0 < 1024; m0 += 32) {
        __syncthreads();
        float4 va = *(const float4*)&LQ[(size_t)lrow * 1024 + m0 + lm4];
        float4 vb = *(const float4*)&LK[(size_t)lrow * 1024 + m0 + lm4];
        Aq[lrow * 37 + lm4 + 0] = va.x; Aq[lrow * 37 + lm4 + 1] = va.y;
        Aq[lrow * 37 + lm4 + 2] = va.z; Aq[lrow * 37 + lm4 + 3] = va.w;
        Bk[lrow * 37 + lm4 + 0] = vb.x; Bk[lrow * 37 + lm4 + 1] = vb.y;
        Bk[lrow * 37 + lm4 + 2] = vb.z; Bk[lrow * 37 + lm4 + 3] = vb.w;
        __syncthreads();
#pragma unroll
        for (int mm = 0; mm < 32; ++mm) {
            float a0 = Aq[(ty * 2 + 0) * 37 + mm];
            float a1 = Aq[(ty * 2 + 1) * 37 + mm];
            float b0 = Bk[(tx * 2 + 0) * 37 + mm];
            float b1 = Bk[(tx * 2 + 1) * 37 + mm];
            acc00 = fmaf(a0, b0, acc00); acc01 = fmaf(a0, b1, acc01);
            acc10 = fmaf(a1, b0, acc10); acc11 = fmaf(a1, b1, acc11);
        }
    }
    const float* qqp = ssq + (size_t)b * 128 + q0;
    const float* kkp = ssq + NM + (size_t)b * 128 + k0;
    const int q = ty * 2, k = tx * 2;
    float* wrow0 = wbuf + ((size_t)b * 128 + q0 + q) * 128 + k0 + k;
    float* wrow1 = wrow0 + 128;
    float e;
    e = fmaxf(qqp[q] + kkp[k] - 2.0f * acc00, 0.0f);
    wrow0[0] = 1.0f / (1.0f + log1pf(e));
    e = fmaxf(qqp[q] + kkp[k + 1] - 2.0f * acc01, 0.0f);
    wrow0[1] = 1.0f / (1.0f + log1pf(e));
    e = fmaxf(qqp[q + 1] + kkp[k] - 2.0f * acc10, 0.0f);
    wrow1[0] = 1.0f / (1.0f + log1pf(e));
    e = fmaxf(qqp[q + 1] + kkp[k + 1] - 2.0f * acc11, 0.0f);
    wrow1[1] = 1.0f / (1.0f + log1pf(e));
}

// ---------------------------------------------------------------------------
// K3b: in-place softmax over the QUERY axis (column-wise on [q][k])
// ---------------------------------------------------------------------------
__global__ __launch_bounds__(256) void softmax_kernel(float* __restrict__ wbuf)
{
    __shared__ float crcp[128];
    const int t = threadIdx.x;
    float* wb = wbuf + (size_t)blockIdx.x * 16384;
    if (t < 128) {
        float ssum = 0.f;
        for (int q = 0; q < 128; ++q) ssum += expf(wb[q * 128 + t]);
        crcp[t] = 1.0f / ssum;
    }
    __syncthreads();
    for (int i = t; i < 16384; i += 256)
        wb[i] = expf(wb[i]) * crcp[i & 127];
}

// ---------------------------------------------------------------------------
// K4: mean_log[b,i,:] = sum_j soft[b,j,i] * LV[b,j,:]
// ---------------------------------------------------------------------------
__global__ __launch_bounds__(256) void meanlog_kernel(
    const float* __restrict__ soft, const float* __restrict__ LV,
    float* __restrict__ ML)
{
    __shared__ float Wt[32 * 129];
    __shared__ __align__(16) float Bl[32 * 260];
    const int b  = blockIdx.z;
    const int i0 = blockIdx.y * 32;
    const int c0 = blockIdx.x * 256;
    const int t  = threadIdx.x;
    const float* sp = soft + (size_t)b * 16384;
#pragma unroll
    for (int jb = 0; jb < 4; ++jb) {
        int j  = jb * 32 + (t >> 3);
        int i4 = (t & 7) * 4;
        float4 v = *(const float4*)&sp[(size_t)j * 128 + i0 + i4];
        Wt[(i4 + 0) * 129 + j] = v.x;
        Wt[(i4 + 1) * 129 + j] = v.y;
        Wt[(i4 + 2) * 129 + j] = v.z;
        Wt[(i4 + 3) * 129 + j] = v.w;
    }
    float acc[32];
#pragma unroll
    for (int i = 0; i < 32; ++i) acc[i] = 0.f;
    const float* lv = LV + (size_t)2 * NM * 1024 + (size_t)b * 128 * 1024 + c0;
    for (int j0 = 0; j0 < 128; j0 += 32) {
        __syncthreads();
#pragma unroll
        for (int jj8 = 0; jj8 < 8; ++jj8) {
            int j  = jj8 * 4 + (t >> 6);
            int c4 = (t & 63) * 4;
            *(float4*)&Bl[j * 260 + c4] =
                *(const float4*)&lv[(size_t)(j0 + j) * 1024 + c4];
        }
        __syncthreads();
#pragma unroll
        for (int jj = 0; jj < 32; ++jj) {
            float v = Bl[jj * 260 + t];
#pragma unroll
            for (int i = 0; i < 32; ++i)
                acc[i] = fmaf(Wt[i * 129 + j0 + jj], v, acc[i]);
        }
    }
    float* mp = ML + ((size_t)b * 128 + i0) * 1024 + c0;
#pragma unroll
    for (int i = 0; i < 32; ++i) mp[(size_t)i * 1024 + t] = acc[i];
}

// ---------------------------------------------------------------------------
// launcher
// ---------------------------------------------------------------------------
extern "C" void kernel_launch(void* const* d_in, const int* in_sizes, int n_in,
                              void* d_out, int out_size, void* d_ws, size_t ws_size,
                              hipStream_t stream)
{
    const float* x  = (const float*)d_in[0];
    const float* Wq = (const float*)d_in[1];
    const float* Wk = (const float*)d_in[2];
    const float* Wv = (const float*)d_in[3];
    float* ws   = (float*)d_ws;
    float* qkv  = ws;                               // 3*NM*1024
    float* ssqp = ws + (size_t)3 * NM * 1024;       // 12288 (padded 16384)
    float* wbuf = ssqp + 16384;                     // NM*128
    float* out  = (float*)d_out;

    bimap_kernel<<<NM, 256, 0, stream>>>(x, Wq, Wk, Wv, qkv);
    log_eig_kernel<<<NMAT3 / 8, 256, 0, stream>>>(qkv, qkv, ssqp);
    qk_weights_kernel<<<dim3(4, 4, 32), 256, 0, stream>>>(qkv, ssqp, wbuf);
    softmax_kernel<<<32, 256, 0, stream>>>(wbuf);
    meanlog_kernel<<<dim3(4, 4, 32), 256, 0, stream>>>(wbuf, qkv, qkv);
    expm_kernel<<<NM / 4, 256, 0, stream>>>(qkv, out);
}